// Round 1
// baseline (2408.754 us; speedup 1.0000x reference)
//
#include <hip/hip_runtime.h>
#include <hip/hip_bf16.h>

// Problem constants (from reference setup_inputs)
constexpr int C = 128;       // channels
constexpr int V = 65536;     // num voxels
constexpr int PP = 8;        // points per block-iteration in MLP kernel
constexpr int MLP_BLOCK = 256;
constexpr size_t SMEM_BYTES = (2 * C * C + PP * C) * sizeof(float); // W1 + W2 + os/h buffer

// -------------------------------------------------------------------------
// Kernel 1: scatter-add pooling (sums + counts) with fp32 atomics.
// One thread per (point, channel-quad): 32 threads/point.
// -------------------------------------------------------------------------
__global__ void scatter_pool(const float* __restrict__ feats,
                             const int* __restrict__ idx,
                             float* __restrict__ pooled,   // [V][C] sums
                             float* __restrict__ counts,   // [V]
                             int n) {
    int t = blockIdx.x * blockDim.x + threadIdx.x;
    int total = n * 32;
    if (t >= total) return;
    int p = t >> 5;
    int q = t & 31;
    int v = idx[p];
    const float4 f = *reinterpret_cast<const float4*>(feats + (size_t)p * C + q * 4);
    float* dst = pooled + (size_t)v * C + q * 4;
    atomicAdd(dst + 0, f.x);
    atomicAdd(dst + 1, f.y);
    atomicAdd(dst + 2, f.z);
    atomicAdd(dst + 3, f.w);
    if (q == 0) atomicAdd(counts + v, 1.0f);
}

// -------------------------------------------------------------------------
// Kernel 2: fused gather + MLP.
//   os  = feats - pooled[idx]/max(counts[idx],1)
//   h   = relu(os @ W1 + b1) * feats
//   out = relu(h @ W2 + b2)
// Block = 256 threads: thread t handles point-slot s = t>>5 (0..7) and
// channel quad q = t&31 (channels 4q..4q+3). W1, W2 staged in LDS (fp32).
// -------------------------------------------------------------------------
__global__ void __launch_bounds__(MLP_BLOCK)
mlp_kernel(const float* __restrict__ feats,
           const float* __restrict__ W1g,
           const float* __restrict__ b1g,
           const float* __restrict__ W2g,
           const float* __restrict__ b2g,
           const int* __restrict__ idx,
           const float* __restrict__ pooled,
           const float* __restrict__ counts,
           float* __restrict__ out,
           int n) {
    extern __shared__ float smem[];
    float* sW1  = smem;                 // [C][C]
    float* sW2  = smem + C * C;         // [C][C]
    float* sbuf = smem + 2 * C * C;     // [PP][C]  (holds os, then h)

    const int t = threadIdx.x;
    const int q = t & 31;   // channel quad
    const int s = t >> 5;   // point slot

    // Stage weights into LDS (coalesced float4).
    for (int i = t * 4; i < C * C; i += MLP_BLOCK * 4) {
        *reinterpret_cast<float4*>(sW1 + i) = *reinterpret_cast<const float4*>(W1g + i);
        *reinterpret_cast<float4*>(sW2 + i) = *reinterpret_cast<const float4*>(W2g + i);
    }
    const float4 bb1 = *reinterpret_cast<const float4*>(b1g + q * 4);
    const float4 bb2 = *reinterpret_cast<const float4*>(b2g + q * 4);
    __syncthreads();

    for (long long base = (long long)blockIdx.x * PP; base < n;
         base += (long long)gridDim.x * PP) {
        const long long p = base + s;
        const bool valid = p < n;

        float4 f = make_float4(0.f, 0.f, 0.f, 0.f);
        if (valid) {
            f = *reinterpret_cast<const float4*>(feats + (size_t)p * C + q * 4);
            const int v = idx[p];
            const float cnt = fmaxf(counts[v], 1.0f);
            const float rc = 1.0f / cnt;
            const float4 pl = *reinterpret_cast<const float4*>(pooled + (size_t)v * C + q * 4);
            float4 os;
            os.x = f.x - pl.x * rc;
            os.y = f.y - pl.y * rc;
            os.z = f.z - pl.z * rc;
            os.w = f.w - pl.w * rc;
            *reinterpret_cast<float4*>(sbuf + s * C + q * 4) = os;
        } else {
            *reinterpret_cast<float4*>(sbuf + s * C + q * 4) = make_float4(0.f, 0.f, 0.f, 0.f);
        }
        __syncthreads();

        // Layer 1: h = relu(os @ W1 + b1) * f
        float4 acc = bb1;
        {
            const float* br = sbuf + s * C;
#pragma unroll 4
            for (int k = 0; k < C; ++k) {
                const float x = br[k];
                const float4 w = *reinterpret_cast<const float4*>(sW1 + k * C + q * 4);
                acc.x = fmaf(x, w.x, acc.x);
                acc.y = fmaf(x, w.y, acc.y);
                acc.z = fmaf(x, w.z, acc.z);
                acc.w = fmaf(x, w.w, acc.w);
            }
        }
        float4 h;
        h.x = fmaxf(acc.x, 0.f) * f.x;
        h.y = fmaxf(acc.y, 0.f) * f.y;
        h.z = fmaxf(acc.z, 0.f) * f.z;
        h.w = fmaxf(acc.w, 0.f) * f.w;

        __syncthreads();  // everyone done reading os before overwrite
        *reinterpret_cast<float4*>(sbuf + s * C + q * 4) = h;
        __syncthreads();

        // Layer 2: out = relu(h @ W2 + b2)
        float4 acc2 = bb2;
        {
            const float* br = sbuf + s * C;
#pragma unroll 4
            for (int k = 0; k < C; ++k) {
                const float x = br[k];
                const float4 w = *reinterpret_cast<const float4*>(sW2 + k * C + q * 4);
                acc2.x = fmaf(x, w.x, acc2.x);
                acc2.y = fmaf(x, w.y, acc2.y);
                acc2.z = fmaf(x, w.z, acc2.z);
                acc2.w = fmaf(x, w.w, acc2.w);
            }
        }
        if (valid) {
            float4 o;
            o.x = fmaxf(acc2.x, 0.f);
            o.y = fmaxf(acc2.y, 0.f);
            o.z = fmaxf(acc2.z, 0.f);
            o.w = fmaxf(acc2.w, 0.f);
            *reinterpret_cast<float4*>(out + (size_t)p * C + q * 4) = o;
        }
        __syncthreads();  // before next iteration overwrites sbuf
    }
}

// -------------------------------------------------------------------------
// Launch
// -------------------------------------------------------------------------
extern "C" void kernel_launch(void* const* d_in, const int* in_sizes, int n_in,
                              void* d_out, int out_size, void* d_ws, size_t ws_size,
                              hipStream_t stream) {
    const float* feats = (const float*)d_in[0];
    const float* W1    = (const float*)d_in[1];
    const float* b1    = (const float*)d_in[2];
    const float* W2    = (const float*)d_in[3];
    const float* b2    = (const float*)d_in[4];
    const int*   idx   = (const int*)d_in[5];
    float*       out   = (float*)d_out;

    const int n = in_sizes[5];  // number of points

    // Workspace layout: pooled sums [V*C] f32, counts [V] f32
    float* pooled = (float*)d_ws;
    float* counts = pooled + (size_t)V * C;
    const size_t zero_bytes = ((size_t)V * C + V) * sizeof(float);

    hipMemsetAsync(d_ws, 0, zero_bytes, stream);

    // Scatter-add pooling
    {
        const long long total = (long long)n * 32;
        const int blk = 256;
        const int grid = (int)((total + blk - 1) / blk);
        scatter_pool<<<grid, blk, 0, stream>>>(feats, idx, pooled, counts, n);
    }

    // Fused MLP (needs >64KB dynamic LDS)
    hipFuncSetAttribute((const void*)mlp_kernel,
                        hipFuncAttributeMaxDynamicSharedMemorySize,
                        (int)SMEM_BYTES);
    {
        const int grid = 512;
        mlp_kernel<<<grid, MLP_BLOCK, SMEM_BYTES, stream>>>(
            feats, W1, b1, W2, b2, idx, pooled, counts, out, n);
    }
}

// Round 2
// 595.622 us; speedup vs baseline: 4.0441x; 4.0441x over previous
//
#include <hip/hip_runtime.h>
#include <hip/hip_fp16.h>

typedef _Float16 f16;
typedef _Float16 f16x8 __attribute__((ext_vector_type(8)));
typedef float f32x4 __attribute__((ext_vector_type(4)));

constexpr int C = 128;     // channels
constexpr int V = 65536;   // voxels
constexpr int PTS = 64;    // points per block iteration
constexpr int BLOCK = 256; // 4 waves

union U16 { uint4 u; f16x8 h; };

// -------------------------------------------------------------------------
// Kernel 1: scatter-add pooling with packed f16 atomics.
// Thread t handles point p = t>>4, channel block (t&15)*8 (8 channels).
// -------------------------------------------------------------------------
__global__ void scatter_pool(const float* __restrict__ feats,
                             const int* __restrict__ idx,
                             __half* __restrict__ pooled,   // [V][C] f16 sums
                             float* __restrict__ counts,    // [V]
                             int n) {
    int t = blockIdx.x * blockDim.x + threadIdx.x;
    if (t >= n * 16) return;
    int p = t >> 4;
    int b = (t & 15) * 8;
    int v = idx[p];
    const float4 f0 = *reinterpret_cast<const float4*>(feats + (size_t)p * C + b);
    const float4 f1 = *reinterpret_cast<const float4*>(feats + (size_t)p * C + b + 4);
    __half2* dst = reinterpret_cast<__half2*>(pooled + (size_t)v * C + b);
    unsafeAtomicAdd(dst + 0, __floats2half2_rn(f0.x, f0.y));
    unsafeAtomicAdd(dst + 1, __floats2half2_rn(f0.z, f0.w));
    unsafeAtomicAdd(dst + 2, __floats2half2_rn(f1.x, f1.y));
    unsafeAtomicAdd(dst + 3, __floats2half2_rn(f1.z, f1.w));
    if ((t & 15) == 0) atomicAdd(counts + v, 1.0f);
}

// -------------------------------------------------------------------------
// Kernel 2: fused gather + 2-layer MLP via f16 MFMA (16x16x32).
//   os  = feats - pooled[idx]/max(counts,1)   (staged in LDS, f16, swizzled)
//   h   = relu(os @ W1 + b1) * feats          (LDS round-trip, f16, swizzled)
//   out = relu(h @ W2 + b2)                   (fp32 global store)
// Each wave owns 32 output channels; W1/W2 fragments live in registers.
// -------------------------------------------------------------------------
__global__ void __launch_bounds__(BLOCK, 2)
mlp_mfma(const float* __restrict__ feats,
         const float* __restrict__ W1g,
         const float* __restrict__ b1g,
         const float* __restrict__ W2g,
         const float* __restrict__ b2g,
         const int* __restrict__ idx,
         const __half* __restrict__ pooled,
         const float* __restrict__ counts,
         float* __restrict__ out,
         int n) {
    __shared__ f16 os_lds[PTS * C];  // 16 KB, XOR-swizzled rows
    __shared__ f16 f_lds[PTS * C];   // 16 KB
    __shared__ f16 h_lds[PTS * C];   // 16 KB

    const int t = threadIdx.x;
    const int lane = t & 63;
    const int wv = t >> 6;          // wave id 0..3
    const int l15 = lane & 15;
    const int lg = lane >> 4;       // lane group 0..3
    const int chBase = 32 * wv;     // this wave's output-channel base

    // ---- Load weight fragments into registers (once per block) ----------
    // B-fragment for 16x16x32: lane holds col = lane&15, k = (lane>>4)*8 + j.
    // (Same assumed k-map used for A-fragments -> any k-permutation cancels.)
    const int ch0 = chBase + l15;
    const int ch1 = chBase + 16 + l15;
    f16x8 w1f[2][4], w2f[2][4];
#pragma unroll
    for (int m = 0; m < 2; ++m) {
        const int ch = (m == 0) ? ch0 : ch1;
#pragma unroll
        for (int s = 0; s < 4; ++s) {
            f16x8 a, b;
#pragma unroll
            for (int j = 0; j < 8; ++j) {
                const int k = s * 32 + lg * 8 + j;
                a[j] = (f16)W1g[k * C + ch];
                b[j] = (f16)W2g[k * C + ch];
            }
            w1f[m][s] = a;
            w2f[m][s] = b;
        }
    }
    const float b1v[2] = {b1g[ch0], b1g[ch1]};
    const float b2v[2] = {b2g[ch0], b2g[ch1]};

    // staging decomposition: thread covers point sp, channels sc..sc+31
    const int sp = t >> 2;
    const int sc = (t & 3) * 32;

    for (long long base = (long long)blockIdx.x * PTS; base < n;
         base += (long long)gridDim.x * PTS) {
        // ---- Stage os (= f - mean) and f into LDS as f16, swizzled ------
        {
            const long long p = base + sp;
            union { float4 v[8]; float f[32]; } ff;
            union { uint4 u[4]; __half h[32]; } pl;
            float rc = 0.f;
            if (p < n) {
#pragma unroll
                for (int j = 0; j < 8; ++j)
                    ff.v[j] = *reinterpret_cast<const float4*>(feats + (size_t)p * C + sc + j * 4);
                const int v = idx[p];
                rc = 1.0f / fmaxf(counts[v], 1.0f);
                const uint4* pp = reinterpret_cast<const uint4*>(pooled + (size_t)v * C + sc);
#pragma unroll
                for (int j = 0; j < 4; ++j) pl.u[j] = pp[j];
            } else {
#pragma unroll
                for (int j = 0; j < 8; ++j) ff.v[j] = make_float4(0.f, 0.f, 0.f, 0.f);
#pragma unroll
                for (int j = 0; j < 4; ++j) pl.u[j] = make_uint4(0, 0, 0, 0);
            }
            union { uint4 u[4]; f16 h[32]; } osv, fvh;
#pragma unroll
            for (int j = 0; j < 32; ++j) {
                const float fj = ff.f[j];
                const float mj = __half2float(pl.h[j]) * rc;
                osv.h[j] = (f16)(fj - mj);
                fvh.h[j] = (f16)fj;
            }
#pragma unroll
            for (int u = 0; u < 4; ++u) {
                const int byte = (sp * 256 + (sc + u * 8) * 2) ^ ((sp & 7) << 4);
                *reinterpret_cast<uint4*>(reinterpret_cast<char*>(os_lds) + byte) = osv.u[u];
                *reinterpret_cast<uint4*>(reinterpret_cast<char*>(f_lds) + byte) = fvh.u[u];
            }
        }
        __syncthreads();  // staging done; also guarantees prior-iter h reads done

        // ---- Layer 1: acc = os @ W1 + b1 --------------------------------
        f32x4 acc[2][4];
#pragma unroll
        for (int m = 0; m < 2; ++m)
#pragma unroll
            for (int q = 0; q < 4; ++q)
                acc[m][q] = (f32x4){b1v[m], b1v[m], b1v[m], b1v[m]};

#pragma unroll
        for (int s = 0; s < 4; ++s) {
            f16x8 af[4];
#pragma unroll
            for (int q = 0; q < 4; ++q) {
                const int p = q * 16 + l15;
                const int byte = (p * 256 + (s * 32 + lg * 8) * 2) ^ ((p & 7) << 4);
                U16 tmp;
                tmp.u = *reinterpret_cast<const uint4*>(reinterpret_cast<const char*>(os_lds) + byte);
                af[q] = tmp.h;
            }
#pragma unroll
            for (int m = 0; m < 2; ++m)
#pragma unroll
                for (int q = 0; q < 4; ++q)
                    acc[m][q] = __builtin_amdgcn_mfma_f32_16x16x32_f16(af[q], w1f[m][s], acc[m][q], 0, 0, 0);
        }

        // ---- h = relu(acc) * f, write to h_lds (f16, swizzled) ----------
        // C/D layout: col = lane&15 (channel), row = (lane>>4)*4 + reg (point)
#pragma unroll
        for (int m = 0; m < 2; ++m) {
            const int ch = chBase + m * 16 + l15;
#pragma unroll
            for (int q = 0; q < 4; ++q)
#pragma unroll
                for (int r = 0; r < 4; ++r) {
                    const int p = q * 16 + lg * 4 + r;
                    const int byte = (p * 256 + ch * 2) ^ ((p & 7) << 4);
                    const float fval = (float)*reinterpret_cast<const f16*>(
                        reinterpret_cast<const char*>(f_lds) + byte);
                    const float hv = fmaxf(acc[m][q][r], 0.f) * fval;
                    *reinterpret_cast<f16*>(reinterpret_cast<char*>(h_lds) + byte) = (f16)hv;
                }
        }
        __syncthreads();  // h complete before layer 2 reads

        // ---- Layer 2: acc2 = h @ W2 + b2, relu, store -------------------
        f32x4 acc2[2][4];
#pragma unroll
        for (int m = 0; m < 2; ++m)
#pragma unroll
            for (int q = 0; q < 4; ++q)
                acc2[m][q] = (f32x4){b2v[m], b2v[m], b2v[m], b2v[m]};

#pragma unroll
        for (int s = 0; s < 4; ++s) {
            f16x8 af[4];
#pragma unroll
            for (int q = 0; q < 4; ++q) {
                const int p = q * 16 + l15;
                const int byte = (p * 256 + (s * 32 + lg * 8) * 2) ^ ((p & 7) << 4);
                U16 tmp;
                tmp.u = *reinterpret_cast<const uint4*>(reinterpret_cast<const char*>(h_lds) + byte);
                af[q] = tmp.h;
            }
#pragma unroll
            for (int m = 0; m < 2; ++m)
#pragma unroll
                for (int q = 0; q < 4; ++q)
                    acc2[m][q] = __builtin_amdgcn_mfma_f32_16x16x32_f16(af[q], w2f[m][s], acc2[m][q], 0, 0, 0);
        }

#pragma unroll
        for (int m = 0; m < 2; ++m) {
            const int ch = chBase + m * 16 + l15;
#pragma unroll
            for (int q = 0; q < 4; ++q)
#pragma unroll
                for (int r = 0; r < 4; ++r) {
                    const int p = q * 16 + lg * 4 + r;
                    const long long gp = base + p;
                    if (gp < n)
                        out[gp * C + ch] = fmaxf(acc2[m][q][r], 0.f);
                }
        }
        // no barrier needed here: next-iter staging writes os/f only, and the
        // top-of-loop __syncthreads() orders h reuse.
    }
}

// -------------------------------------------------------------------------
// Launch
// -------------------------------------------------------------------------
extern "C" void kernel_launch(void* const* d_in, const int* in_sizes, int n_in,
                              void* d_out, int out_size, void* d_ws, size_t ws_size,
                              hipStream_t stream) {
    const float* feats = (const float*)d_in[0];
    const float* W1    = (const float*)d_in[1];
    const float* b1    = (const float*)d_in[2];
    const float* W2    = (const float*)d_in[3];
    const float* b2    = (const float*)d_in[4];
    const int*   idx   = (const int*)d_in[5];
    float*       out   = (float*)d_out;

    const int n = in_sizes[5];

    // Workspace: pooled f16 sums [V*C], then counts f32 [V]
    __half* pooled = (__half*)d_ws;
    float*  counts = (float*)((char*)d_ws + (size_t)V * C * sizeof(__half));
    const size_t zero_bytes = (size_t)V * C * sizeof(__half) + (size_t)V * sizeof(float);

    hipMemsetAsync(d_ws, 0, zero_bytes, stream);

    {
        const int total = n * 16;
        const int grid = (total + 255) / 256;
        scatter_pool<<<grid, 256, 0, stream>>>(feats, idx, pooled, counts, n);
    }
    {
        const int grid = 1024;
        mlp_mfma<<<grid, BLOCK, 0, stream>>>(feats, W1, b1, W2, b2, idx,
                                             pooled, counts, out, n);
    }
}

// Round 3
// 288.324 us; speedup vs baseline: 8.3543x; 2.0658x over previous
//
#include <hip/hip_runtime.h>
#include <hip/hip_fp16.h>

typedef _Float16 f16;
typedef _Float16 f16x8 __attribute__((ext_vector_type(8)));
typedef float f32x4 __attribute__((ext_vector_type(4)));

constexpr int C = 128;     // channels
constexpr int V = 65536;   // voxels
constexpr int PTS = 64;    // points per block iteration (MLP)
constexpr int BLOCK = 256; // 4 waves

union U16 { uint4 u; f16x8 h; };

// -------------------------------------------------------------------------
// CSR build: histogram -> exclusive scan -> scatter ids
// -------------------------------------------------------------------------
__global__ void hist_kernel(const int* __restrict__ idx, int* __restrict__ cnt, int n) {
    int t = blockIdx.x * blockDim.x + threadIdx.x;
    if (t < n) atomicAdd(&cnt[idx[t]], 1);
}

// 256 blocks x 256 threads; V = 256*256 exactly.
__global__ void scan_block(const int* __restrict__ cnt, int* __restrict__ off,
                           int* __restrict__ bsum) {
    __shared__ int s[256];
    const int i = blockIdx.x * 256 + threadIdx.x;
    const int x = cnt[i];
    s[threadIdx.x] = x;
    __syncthreads();
    for (int d = 1; d < 256; d <<= 1) {
        int y = (threadIdx.x >= d) ? s[threadIdx.x - d] : 0;
        __syncthreads();
        s[threadIdx.x] += y;
        __syncthreads();
    }
    off[i] = s[threadIdx.x] - x;  // exclusive
    if (threadIdx.x == 255) bsum[blockIdx.x] = s[255];
}

__global__ void scan_bsum(int* __restrict__ bsum) {  // 1 block x 256
    __shared__ int s[256];
    const int x = bsum[threadIdx.x];
    s[threadIdx.x] = x;
    __syncthreads();
    for (int d = 1; d < 256; d <<= 1) {
        int y = (threadIdx.x >= d) ? s[threadIdx.x - d] : 0;
        __syncthreads();
        s[threadIdx.x] += y;
        __syncthreads();
    }
    bsum[threadIdx.x] = s[threadIdx.x] - x;  // exclusive
}

__global__ void add_bsum(int* __restrict__ off, const int* __restrict__ bsum) {
    off[blockIdx.x * 256 + threadIdx.x] += bsum[blockIdx.x];
}

// After this kernel, off[v] = inclusive prefix (original off[v] + count[v]).
__global__ void scatter_ids(const int* __restrict__ idx, int* __restrict__ off,
                            int* __restrict__ csr, int n) {
    int t = blockIdx.x * blockDim.x + threadIdx.x;
    if (t < n) {
        const int v = idx[t];
        const int slot = atomicAdd(&off[v], 1);
        csr[slot] = t;
    }
}

// -------------------------------------------------------------------------
// Pooling: one wave per voxel, fp32 accumulation, store f16 MEAN.
// Voxel v range = [v ? off[v-1] : 0, off[v]).
// -------------------------------------------------------------------------
__global__ void __launch_bounds__(256)
pool_csr(const float* __restrict__ feats, const int* __restrict__ csr,
         const int* __restrict__ off, __half* __restrict__ pooled) {
    const int v = blockIdx.x * 4 + (threadIdx.x >> 6);
    const int lane = threadIdx.x & 63;
    const int s = (v == 0) ? 0 : off[v - 1];
    const int e = off[v];
    float ax = 0.f, ay = 0.f;
    for (int j = s; j < e; ++j) {
        const int p = csr[j];
        const float2 f = *reinterpret_cast<const float2*>(feats + (size_t)p * C + lane * 2);
        ax += f.x;
        ay += f.y;
    }
    const float rc = (e > s) ? 1.0f / (float)(e - s) : 0.f;
    *reinterpret_cast<__half2*>(pooled + (size_t)v * C + lane * 2) =
        __floats2half2_rn(ax * rc, ay * rc);
}

// -------------------------------------------------------------------------
// Fused gather + 2-layer MLP via f16 MFMA (16x16x32).
//   os  = feats - pooled_mean[idx]     (staged in LDS, f16, swizzled)
//   h   = relu(os @ W1 + b1) * feats   (LDS round-trip, f16, swizzled)
//   out = relu(h @ W2 + b2)            (fp32 global store)
// -------------------------------------------------------------------------
__global__ void __launch_bounds__(BLOCK, 2)
mlp_mfma(const float* __restrict__ feats,
         const float* __restrict__ W1g,
         const float* __restrict__ b1g,
         const float* __restrict__ W2g,
         const float* __restrict__ b2g,
         const int* __restrict__ idx,
         const __half* __restrict__ pooled,
         float* __restrict__ out,
         int n) {
    __shared__ f16 os_lds[PTS * C];  // 16 KB, XOR-swizzled rows
    __shared__ f16 f_lds[PTS * C];   // 16 KB
    __shared__ f16 h_lds[PTS * C];   // 16 KB

    const int t = threadIdx.x;
    const int lane = t & 63;
    const int wv = t >> 6;
    const int l15 = lane & 15;
    const int lg = lane >> 4;
    const int chBase = 32 * wv;

    // Weight fragments in registers (B-fragment: col = lane&15, k = (lane>>4)*8+j)
    const int ch0 = chBase + l15;
    const int ch1 = chBase + 16 + l15;
    f16x8 w1f[2][4], w2f[2][4];
#pragma unroll
    for (int m = 0; m < 2; ++m) {
        const int ch = (m == 0) ? ch0 : ch1;
#pragma unroll
        for (int s = 0; s < 4; ++s) {
            f16x8 a, b;
#pragma unroll
            for (int j = 0; j < 8; ++j) {
                const int k = s * 32 + lg * 8 + j;
                a[j] = (f16)W1g[k * C + ch];
                b[j] = (f16)W2g[k * C + ch];
            }
            w1f[m][s] = a;
            w2f[m][s] = b;
        }
    }
    const float b1v[2] = {b1g[ch0], b1g[ch1]};
    const float b2v[2] = {b2g[ch0], b2g[ch1]};

    const int sp = t >> 2;
    const int sc = (t & 3) * 32;

    for (long long base = (long long)blockIdx.x * PTS; base < n;
         base += (long long)gridDim.x * PTS) {
        // ---- Stage os (= f - mean) and f into LDS as f16, swizzled ------
        {
            const long long p = base + sp;
            union { float4 v[8]; float f[32]; } ff;
            union { uint4 u[4]; __half h[32]; } pl;
            if (p < n) {
#pragma unroll
                for (int j = 0; j < 8; ++j)
                    ff.v[j] = *reinterpret_cast<const float4*>(feats + (size_t)p * C + sc + j * 4);
                const int v = idx[p];
                const uint4* pp = reinterpret_cast<const uint4*>(pooled + (size_t)v * C + sc);
#pragma unroll
                for (int j = 0; j < 4; ++j) pl.u[j] = pp[j];
            } else {
#pragma unroll
                for (int j = 0; j < 8; ++j) ff.v[j] = make_float4(0.f, 0.f, 0.f, 0.f);
#pragma unroll
                for (int j = 0; j < 4; ++j) pl.u[j] = make_uint4(0, 0, 0, 0);
            }
            union { uint4 u[4]; f16 h[32]; } osv, fvh;
#pragma unroll
            for (int j = 0; j < 32; ++j) {
                const float fj = ff.f[j];
                const float mj = __half2float(pl.h[j]);
                osv.h[j] = (f16)(fj - mj);
                fvh.h[j] = (f16)fj;
            }
#pragma unroll
            for (int u = 0; u < 4; ++u) {
                const int byte = (sp * 256 + (sc + u * 8) * 2) ^ ((sp & 7) << 4);
                *reinterpret_cast<uint4*>(reinterpret_cast<char*>(os_lds) + byte) = osv.u[u];
                *reinterpret_cast<uint4*>(reinterpret_cast<char*>(f_lds) + byte) = fvh.u[u];
            }
        }
        __syncthreads();

        // ---- Layer 1 ----------------------------------------------------
        f32x4 acc[2][4];
#pragma unroll
        for (int m = 0; m < 2; ++m)
#pragma unroll
            for (int q = 0; q < 4; ++q)
                acc[m][q] = (f32x4){b1v[m], b1v[m], b1v[m], b1v[m]};

#pragma unroll
        for (int s = 0; s < 4; ++s) {
            f16x8 af[4];
#pragma unroll
            for (int q = 0; q < 4; ++q) {
                const int p = q * 16 + l15;
                const int byte = (p * 256 + (s * 32 + lg * 8) * 2) ^ ((p & 7) << 4);
                U16 tmp;
                tmp.u = *reinterpret_cast<const uint4*>(reinterpret_cast<const char*>(os_lds) + byte);
                af[q] = tmp.h;
            }
#pragma unroll
            for (int m = 0; m < 2; ++m)
#pragma unroll
                for (int q = 0; q < 4; ++q)
                    acc[m][q] = __builtin_amdgcn_mfma_f32_16x16x32_f16(af[q], w1f[m][s], acc[m][q], 0, 0, 0);
        }

        // ---- h = relu(acc) * f -> h_lds ----------------------------------
#pragma unroll
        for (int m = 0; m < 2; ++m) {
            const int ch = chBase + m * 16 + l15;
#pragma unroll
            for (int q = 0; q < 4; ++q)
#pragma unroll
                for (int r = 0; r < 4; ++r) {
                    const int p = q * 16 + lg * 4 + r;
                    const int byte = (p * 256 + ch * 2) ^ ((p & 7) << 4);
                    const float fval = (float)*reinterpret_cast<const f16*>(
                        reinterpret_cast<const char*>(f_lds) + byte);
                    const float hv = fmaxf(acc[m][q][r], 0.f) * fval;
                    *reinterpret_cast<f16*>(reinterpret_cast<char*>(h_lds) + byte) = (f16)hv;
                }
        }
        __syncthreads();

        // ---- Layer 2 + store --------------------------------------------
        f32x4 acc2[2][4];
#pragma unroll
        for (int m = 0; m < 2; ++m)
#pragma unroll
            for (int q = 0; q < 4; ++q)
                acc2[m][q] = (f32x4){b2v[m], b2v[m], b2v[m], b2v[m]};

#pragma unroll
        for (int s = 0; s < 4; ++s) {
            f16x8 af[4];
#pragma unroll
            for (int q = 0; q < 4; ++q) {
                const int p = q * 16 + l15;
                const int byte = (p * 256 + (s * 32 + lg * 8) * 2) ^ ((p & 7) << 4);
                U16 tmp;
                tmp.u = *reinterpret_cast<const uint4*>(reinterpret_cast<const char*>(h_lds) + byte);
                af[q] = tmp.h;
            }
#pragma unroll
            for (int m = 0; m < 2; ++m)
#pragma unroll
                for (int q = 0; q < 4; ++q)
                    acc2[m][q] = __builtin_amdgcn_mfma_f32_16x16x32_f16(af[q], w2f[m][s], acc2[m][q], 0, 0, 0);
        }

#pragma unroll
        for (int m = 0; m < 2; ++m) {
            const int ch = chBase + m * 16 + l15;
#pragma unroll
            for (int q = 0; q < 4; ++q)
#pragma unroll
                for (int r = 0; r < 4; ++r) {
                    const int p = q * 16 + lg * 4 + r;
                    const long long gp = base + p;
                    if (gp < n)
                        out[gp * C + ch] = fmaxf(acc2[m][q][r], 0.f);
                }
        }
        __syncthreads();  // h_lds reads done before next-iter staging reuses LDS
    }
}

// -------------------------------------------------------------------------
// Launch
// -------------------------------------------------------------------------
extern "C" void kernel_launch(void* const* d_in, const int* in_sizes, int n_in,
                              void* d_out, int out_size, void* d_ws, size_t ws_size,
                              hipStream_t stream) {
    const float* feats = (const float*)d_in[0];
    const float* W1    = (const float*)d_in[1];
    const float* b1    = (const float*)d_in[2];
    const float* W2    = (const float*)d_in[3];
    const float* b2    = (const float*)d_in[4];
    const int*   idx   = (const int*)d_in[5];
    float*       out   = (float*)d_out;

    const int n = in_sizes[5];

    // Workspace layout (all 16B-aligned regions):
    //   cnt[V] int | off[V] int | bsum[256] int | csr[n] int (rounded) | pooled[V*C] f16
    int* cnt  = (int*)d_ws;
    int* off  = cnt + V;
    int* bsum = off + V;
    int* csr  = bsum + 256;
    const int n_round = (n + 3) & ~3;
    __half* pooled = (__half*)(csr + n_round);

    hipMemsetAsync(cnt, 0, (size_t)V * sizeof(int), stream);

    const int gridN = (n + 255) / 256;
    hist_kernel<<<gridN, 256, 0, stream>>>(idx, cnt, n);
    scan_block<<<V / 256, 256, 0, stream>>>(cnt, off, bsum);
    scan_bsum<<<1, 256, 0, stream>>>(bsum);
    add_bsum<<<V / 256, 256, 0, stream>>>(off, bsum);
    scatter_ids<<<gridN, 256, 0, stream>>>(idx, off, csr, n);
    pool_csr<<<V / 4, 256, 0, stream>>>(feats, csr, off, pooled);

    mlp_mfma<<<1024, BLOCK, 0, stream>>>(feats, W1, b1, W2, b2, idx,
                                         pooled, out, n);
}